// Round 10
// baseline (22.211 us; speedup 1.0000x reference)
//
#include <hip/hip_runtime.h>

// ConduitHydrology on a static 1500x1500 raster.
// Link layout: horizontal id = r*(NCOLS-1)+c (tail (r,c) -> head (r,c+1)),
//              vertical   id = NH + r*NCOLS+c (tail (r,c) -> head (r+1,c)).
// link_length constant DX=100 (folded); head/tail implied by raster layout.
// Interior fast path: ne == eff, cnt == 4, center cancels: sum_grad=(E-W)+(S-N).
//
// R9 = R8 with the nontemporal builtins fed clang ext_vector types
// (HIP_vector_type float2 is rejected by __builtin_nontemporal_load).
//  - float2-per-thread, block (128,4), 18000 waves, XCD row-band swizzle
//  - shfl-halo: eW/eE + horizontal-sv from neighbor lanes' registers
//    (parity-aligned pair; patch loads at wave/tile seams)
//  - nontemporal loads on no-reuse streams (q, g, sv) + out store;
//    eff stays cached (N/S halo reuse).

#define NROWS 1500
#define NCOLS 1500
#define NH    (NROWS * (NCOLS - 1))
#define GX    6
#define GY    375
#define NWG   (GX * GY)                // 2250

#define OPENING_COEFF 1.3455e-09f
#define CLOSURE_COEFF 7.11e-24f
#define INV_SCALE_CUTOFF (1.0f / 5.74f)
#define STEP_HEIGHT 0.03f
#define INV_SEC_PER_A (1.0f / 31556926.0f)
#define INV_DX 0.01f

typedef float v2f __attribute__((ext_vector_type(2)));

__device__ __forceinline__ float finish_node(float sum_grad, float sum_sv, float rcnt,
                                             float ne_c, float q, float g_geom)
{
    const float gradient = sum_grad * (INV_DX * rcnt) + g_geom;
    const float cavity   = fabsf(sum_sv * rcnt) * (STEP_HEIGHT * INV_SEC_PER_A);
    const float num = OPENING_COEFF * q * gradient + cavity;
    const float den = cavity * INV_SCALE_CUTOFF + CLOSURE_COEFF * ne_c * ne_c * ne_c;
    float conduit = num * __builtin_amdgcn_rcpf(den);
    conduit = (conduit < 1e-6f) ? 1e-6f : conduit;
    // conduit >= 1e-6 > 0: pow(x,1.25) == exp2(1.25*log2(x))
    const float p125 = __builtin_amdgcn_exp2f(1.25f * __builtin_amdgcn_logf(conduit));
    const float ag   = fabsf(gradient);
    return q - OPENING_COEFF * p125 * (gradient * __builtin_amdgcn_rsqf(ag));
}

__device__ __forceinline__ float slow_node(const float* __restrict__ eff,
                                           const float* __restrict__ discharge,
                                           const float* __restrict__ geom,
                                           const float* __restrict__ over,
                                           const float* __restrict__ sv,
                                           const int*   __restrict__ status,
                                           int r, int c)
{
    const int j0 = r * NCOLS + c;
    const float ne_c = status[j0] != 0 ? over[j0] : eff[j0];
    float sum_grad = 0.0f, sum_sv = 0.0f;
    if (c > 0) {
        const int j = j0 - 1;
        const float ne = status[j] != 0 ? over[j] : eff[j];
        sum_grad += (ne_c - ne);
        sum_sv   += sv[r * (NCOLS - 1) + (c - 1)];
    }
    if (c < NCOLS - 1) {
        const int j = j0 + 1;
        const float ne = status[j] != 0 ? over[j] : eff[j];
        sum_grad += (ne - ne_c);
        sum_sv   += sv[r * (NCOLS - 1) + c];
    }
    if (r > 0) {
        const int j = j0 - NCOLS;
        const float ne = status[j] != 0 ? over[j] : eff[j];
        sum_grad += (ne_c - ne);
        sum_sv   += sv[NH + (r - 1) * NCOLS + c];
    }
    if (r < NROWS - 1) {
        const int j = j0 + NCOLS;
        const float ne = status[j] != 0 ? over[j] : eff[j];
        sum_grad += (ne - ne_c);
        sum_sv   += sv[NH + r * NCOLS + c];
    }
    const int cnt = (c > 0) + (c < NCOLS - 1) + (r > 0) + (r < NROWS - 1);
    const float rcnt = (cnt == 4) ? 0.25f : ((cnt == 3) ? (1.0f / 3.0f) : 0.5f);
    return finish_node(sum_grad, sum_sv, rcnt, ne_c, discharge[j0], geom[j0]);
}

__global__ __launch_bounds__(512)
void conduit_kernel(const float* __restrict__ eff,
                    const float* __restrict__ discharge,
                    const float* __restrict__ geom,
                    const float* __restrict__ over,
                    const float* __restrict__ sv,
                    const int*   __restrict__ status,
                    float* __restrict__ out)
{
    // bijective XCD chunk swizzle: nwg=2250, 8 XCDs -> q=281, rem=2
    const int orig = blockIdx.x;
    const int xcd  = orig & 7;
    const int base = orig >> 3;
    const int lin  = (xcd < 2) ? xcd * 282 + base
                               : 2 * 282 + (xcd - 2) * 281 + base;
    const int bx = lin % GX;           // col tile
    const int by = lin / GX;           // row tile (contiguous band per XCD)

    const int c0 = bx * 256 + threadIdx.x * 2;
    const int r  = by * 4 + threadIdx.y;
    if (c0 >= NCOLS) return;
    const int idx = r * NCOLS + c0;

    const bool interior = (r >= 2) && (r <= NROWS - 3) && (c0 >= 2) && (c0 <= NCOLS - 4);

    if (interior) {
        const int lane = threadIdx.x & 63;            // waves are x-contiguous
        const bool patchW = (lane == 0)  || (c0 == 2);      // shfl source invalid/absent
        const bool patchE = (lane == 63) || (c0 == NCOLS - 4);

        const float2 eC = *(const float2*)(eff + idx);
        const float2 eN = *(const float2*)(eff + idx - NCOLS);
        const float2 eS = *(const float2*)(eff + idx + NCOLS);
        const v2f q2 = __builtin_nontemporal_load((const v2f*)(discharge + idx));
        const v2f g2 = __builtin_nontemporal_load((const v2f*)(geom + idx));
        const v2f vN = __builtin_nontemporal_load((const v2f*)(sv + NH + (r - 1) * NCOLS + c0));
        const v2f vS = __builtin_nontemporal_load((const v2f*)(sv + NH + r * NCOLS + c0));

        // eW/eE from neighbor lanes' registers
        float eW = __shfl_up(eC.y, 1, 64);
        float eE = __shfl_down(eC.x, 1, 64);
        if (patchW) eW = eff[idx - 1];
        if (patchE) eE = eff[idx + 2];

        // horizontal links c0-1, c0, c0+1: parity-aligned pair + shfl
        const int R = r * (NCOLS - 1);
        float h0, h1, h2;
        if ((r & 1) == 0) {
            // R even, c0 even -> [R+c0, R+c0+1] aligned = (h1, h2)
            const v2f hp = __builtin_nontemporal_load((const v2f*)(sv + R + c0));
            h1 = hp.x; h2 = hp.y;
            h0 = __shfl_up(hp.y, 1, 64);              // lane-1 pair.y = h@c0-1
            if (patchW) h0 = sv[R + c0 - 1];
        } else {
            // R odd, c0-1 odd -> [R+c0-1, R+c0] aligned = (h0, h1)
            const v2f hp = __builtin_nontemporal_load((const v2f*)(sv + R + c0 - 1));
            h0 = hp.x; h1 = hp.y;
            h2 = __shfl_down(hp.x, 1, 64);            // lane+1 pair.x = h@c0+1
            if (patchE) h2 = sv[R + c0 + 1];
        }

        v2f res;
        res.x = finish_node((eC.y - eW) + (eS.x - eN.x), h0 + h1 + vN.x + vS.x,
                            0.25f, eC.x, q2.x, g2.x);
        res.y = finish_node((eE - eC.x) + (eS.y - eN.y), h1 + h2 + vN.y + vS.y,
                            0.25f, eC.y, q2.y, g2.y);
        __builtin_nontemporal_store(res, (v2f*)(out + idx));
    } else {
        // rim-adjacent / ragged-edge slow path: full per-node logic
        #pragma unroll
        for (int k = 0; k < 2; ++k) {
            const int c = c0 + k;
            if (c >= NCOLS) break;
            out[r * NCOLS + c] = slow_node(eff, discharge, geom, over, sv, status, r, c);
        }
    }
}

extern "C" void kernel_launch(void* const* d_in, const int* in_sizes, int n_in,
                              void* d_out, int out_size, void* d_ws, size_t ws_size,
                              hipStream_t stream) {
    const float* eff       = (const float*)d_in[0];
    const float* discharge = (const float*)d_in[1];
    const float* geom      = (const float*)d_in[2];
    const float* over      = (const float*)d_in[3];
    const float* sv        = (const float*)d_in[4];
    // d_in[5]=link_length constant; d_in[6]=head, d_in[7]=tail implied
    const int*   status    = (const int*)d_in[8];
    float* out = (float*)d_out;

    dim3 block(128, 4, 1);
    dim3 grid(NWG, 1, 1);
    conduit_kernel<<<grid, block, 0, stream>>>(eff, discharge, geom, over, sv, status, out);
}

// Round 11
// 19.760 us; speedup vs baseline: 1.1240x; 1.1240x over previous
//
#include <hip/hip_runtime.h>

// ConduitHydrology on a static 1500x1500 raster.
// Link layout: horizontal id = r*(NCOLS-1)+c (tail (r,c) -> head (r,c+1)),
//              vertical   id = NH + r*NCOLS+c (tail (r,c) -> head (r+1,c)).
// link_length constant DX=100 (folded); head/tail implied by raster layout.
// Interior fast path: ne == eff, cnt == 4, center cancels: sum_grad=(E-W)+(S-N).
//
// R10 = R7 (best: 18.14us — float2/thread, block (128,4), 18000 waves,
// XCD row-band swizzle, all loads plain/cached) + nontemporal ONLY on
// zero-reuse streams: discharge, geom, out. sv/eff stay cached (sv vertical
// rows are read twice; eff has N/S halo reuse — R9 proved nt on sv regresses).

#define NROWS 1500
#define NCOLS 1500
#define NH    (NROWS * (NCOLS - 1))
#define GX    6
#define GY    375
#define NWG   (GX * GY)                // 2250

#define OPENING_COEFF 1.3455e-09f
#define CLOSURE_COEFF 7.11e-24f
#define INV_SCALE_CUTOFF (1.0f / 5.74f)
#define STEP_HEIGHT 0.03f
#define INV_SEC_PER_A (1.0f / 31556926.0f)
#define INV_DX 0.01f

typedef float v2f __attribute__((ext_vector_type(2)));

__device__ __forceinline__ float finish_node(float sum_grad, float sum_sv, float rcnt,
                                             float ne_c, float q, float g_geom)
{
    const float gradient = sum_grad * (INV_DX * rcnt) + g_geom;
    const float cavity   = fabsf(sum_sv * rcnt) * (STEP_HEIGHT * INV_SEC_PER_A);
    const float num = OPENING_COEFF * q * gradient + cavity;
    const float den = cavity * INV_SCALE_CUTOFF + CLOSURE_COEFF * ne_c * ne_c * ne_c;
    float conduit = num * __builtin_amdgcn_rcpf(den);
    conduit = (conduit < 1e-6f) ? 1e-6f : conduit;
    // conduit >= 1e-6 > 0: pow(x,1.25) == exp2(1.25*log2(x))
    const float p125 = __builtin_amdgcn_exp2f(1.25f * __builtin_amdgcn_logf(conduit));
    const float ag   = fabsf(gradient);
    return q - OPENING_COEFF * p125 * (gradient * __builtin_amdgcn_rsqf(ag));
}

__device__ __forceinline__ float slow_node(const float* __restrict__ eff,
                                           const float* __restrict__ discharge,
                                           const float* __restrict__ geom,
                                           const float* __restrict__ over,
                                           const float* __restrict__ sv,
                                           const int*   __restrict__ status,
                                           int r, int c)
{
    const int j0 = r * NCOLS + c;
    const float ne_c = status[j0] != 0 ? over[j0] : eff[j0];
    float sum_grad = 0.0f, sum_sv = 0.0f;
    if (c > 0) {
        const int j = j0 - 1;
        const float ne = status[j] != 0 ? over[j] : eff[j];
        sum_grad += (ne_c - ne);
        sum_sv   += sv[r * (NCOLS - 1) + (c - 1)];
    }
    if (c < NCOLS - 1) {
        const int j = j0 + 1;
        const float ne = status[j] != 0 ? over[j] : eff[j];
        sum_grad += (ne - ne_c);
        sum_sv   += sv[r * (NCOLS - 1) + c];
    }
    if (r > 0) {
        const int j = j0 - NCOLS;
        const float ne = status[j] != 0 ? over[j] : eff[j];
        sum_grad += (ne_c - ne);
        sum_sv   += sv[NH + (r - 1) * NCOLS + c];
    }
    if (r < NROWS - 1) {
        const int j = j0 + NCOLS;
        const float ne = status[j] != 0 ? over[j] : eff[j];
        sum_grad += (ne - ne_c);
        sum_sv   += sv[NH + r * NCOLS + c];
    }
    const int cnt = (c > 0) + (c < NCOLS - 1) + (r > 0) + (r < NROWS - 1);
    const float rcnt = (cnt == 4) ? 0.25f : ((cnt == 3) ? (1.0f / 3.0f) : 0.5f);
    return finish_node(sum_grad, sum_sv, rcnt, ne_c, discharge[j0], geom[j0]);
}

__global__ __launch_bounds__(512)
void conduit_kernel(const float* __restrict__ eff,
                    const float* __restrict__ discharge,
                    const float* __restrict__ geom,
                    const float* __restrict__ over,
                    const float* __restrict__ sv,
                    const int*   __restrict__ status,
                    float* __restrict__ out)
{
    // bijective XCD chunk swizzle: nwg=2250, 8 XCDs -> q=281, rem=2
    const int orig = blockIdx.x;
    const int xcd  = orig & 7;
    const int base = orig >> 3;
    const int lin  = (xcd < 2) ? xcd * 282 + base
                               : 2 * 282 + (xcd - 2) * 281 + base;
    const int bx = lin % GX;           // col tile
    const int by = lin / GX;           // row tile (contiguous band per XCD)

    const int c0 = bx * 256 + threadIdx.x * 2;
    const int r  = by * 4 + threadIdx.y;
    if (c0 >= NCOLS) return;
    const int idx = r * NCOLS + c0;

    const bool interior = (r >= 2) && (r <= NROWS - 3) && (c0 >= 2) && (c0 <= NCOLS - 4);

    if (interior) {
        const float2 eC = *(const float2*)(eff + idx);
        const float2 eN = *(const float2*)(eff + idx - NCOLS);
        const float2 eS = *(const float2*)(eff + idx + NCOLS);
        const float  eW = eff[idx - 1];
        const float  eE = eff[idx + 2];
        const v2f q2 = __builtin_nontemporal_load((const v2f*)(discharge + idx));
        const v2f g2 = __builtin_nontemporal_load((const v2f*)(geom + idx));
        const float2 vN = *(const float2*)(sv + NH + (r - 1) * NCOLS + c0);
        const float2 vS = *(const float2*)(sv + NH + r * NCOLS + c0);
        const int hb = r * (NCOLS - 1) + c0 - 1;   // horizontal links c0-1, c0, c0+1
        const float h0 = sv[hb], h1 = sv[hb + 1], h2 = sv[hb + 2];

        v2f res;
        res.x = finish_node((eC.y - eW) + (eS.x - eN.x), h0 + h1 + vN.x + vS.x,
                            0.25f, eC.x, q2.x, g2.x);
        res.y = finish_node((eE - eC.x) + (eS.y - eN.y), h1 + h2 + vN.y + vS.y,
                            0.25f, eC.y, q2.y, g2.y);
        __builtin_nontemporal_store(res, (v2f*)(out + idx));
    } else {
        // rim-adjacent / ragged-edge slow path: full per-node logic
        #pragma unroll
        for (int k = 0; k < 2; ++k) {
            const int c = c0 + k;
            if (c >= NCOLS) break;
            out[r * NCOLS + c] = slow_node(eff, discharge, geom, over, sv, status, r, c);
        }
    }
}

extern "C" void kernel_launch(void* const* d_in, const int* in_sizes, int n_in,
                              void* d_out, int out_size, void* d_ws, size_t ws_size,
                              hipStream_t stream) {
    const float* eff       = (const float*)d_in[0];
    const float* discharge = (const float*)d_in[1];
    const float* geom      = (const float*)d_in[2];
    const float* over      = (const float*)d_in[3];
    const float* sv        = (const float*)d_in[4];
    // d_in[5]=link_length constant; d_in[6]=head, d_in[7]=tail implied
    const int*   status    = (const int*)d_in[8];
    float* out = (float*)d_out;

    dim3 block(128, 4, 1);
    dim3 grid(NWG, 1, 1);
    conduit_kernel<<<grid, block, 0, stream>>>(eff, discharge, geom, over, sv, status, out);
}

// Round 12
// 18.097 us; speedup vs baseline: 1.2273x; 1.0919x over previous
//
#include <hip/hip_runtime.h>

// ConduitHydrology on a static 1500x1500 raster — FINAL (R7 structure, best: 18.14us).
// Link layout: horizontal id = r*(NCOLS-1)+c (tail (r,c) -> head (r,c+1)),
//              vertical   id = NH + r*NCOLS+c (tail (r,c) -> head (r+1,c)).
// link_length constant DX=100 (folded); head/tail implied by raster layout.
// Interior fast path: ne == eff, cnt == 4, center cancels: sum_grad=(E-W)+(S-N).
//
// Structure: 2 cols/thread (float2), block (128,4)=512 threads covering
// 256 cols x 4 rows. NWG=2250 -> 18000 waves (max TLP; this plateau won:
// ILP variants R4/R6 and shfl/nontemporal variants R8-R10 all regressed).
// Bijective XCD chunk swizzle (q=281, rem=2) -> contiguous row band per XCD.

#define NROWS 1500
#define NCOLS 1500
#define NH    (NROWS * (NCOLS - 1))
#define GX    6
#define GY    375
#define NWG   (GX * GY)                // 2250

#define OPENING_COEFF 1.3455e-09f
#define CLOSURE_COEFF 7.11e-24f
#define INV_SCALE_CUTOFF (1.0f / 5.74f)
#define STEP_HEIGHT 0.03f
#define INV_SEC_PER_A (1.0f / 31556926.0f)
#define INV_DX 0.01f

__device__ __forceinline__ float finish_node(float sum_grad, float sum_sv, float rcnt,
                                             float ne_c, float q, float g_geom)
{
    const float gradient = sum_grad * (INV_DX * rcnt) + g_geom;
    const float cavity   = fabsf(sum_sv * rcnt) * (STEP_HEIGHT * INV_SEC_PER_A);
    const float num = OPENING_COEFF * q * gradient + cavity;
    const float den = cavity * INV_SCALE_CUTOFF + CLOSURE_COEFF * ne_c * ne_c * ne_c;
    float conduit = num * __builtin_amdgcn_rcpf(den);
    conduit = (conduit < 1e-6f) ? 1e-6f : conduit;
    // conduit >= 1e-6 > 0: pow(x,1.25) == exp2(1.25*log2(x))
    const float p125 = __builtin_amdgcn_exp2f(1.25f * __builtin_amdgcn_logf(conduit));
    const float ag   = fabsf(gradient);
    return q - OPENING_COEFF * p125 * (gradient * __builtin_amdgcn_rsqf(ag));
}

__device__ __forceinline__ float slow_node(const float* __restrict__ eff,
                                           const float* __restrict__ discharge,
                                           const float* __restrict__ geom,
                                           const float* __restrict__ over,
                                           const float* __restrict__ sv,
                                           const int*   __restrict__ status,
                                           int r, int c)
{
    const int j0 = r * NCOLS + c;
    const float ne_c = status[j0] != 0 ? over[j0] : eff[j0];
    float sum_grad = 0.0f, sum_sv = 0.0f;
    if (c > 0) {
        const int j = j0 - 1;
        const float ne = status[j] != 0 ? over[j] : eff[j];
        sum_grad += (ne_c - ne);
        sum_sv   += sv[r * (NCOLS - 1) + (c - 1)];
    }
    if (c < NCOLS - 1) {
        const int j = j0 + 1;
        const float ne = status[j] != 0 ? over[j] : eff[j];
        sum_grad += (ne - ne_c);
        sum_sv   += sv[r * (NCOLS - 1) + c];
    }
    if (r > 0) {
        const int j = j0 - NCOLS;
        const float ne = status[j] != 0 ? over[j] : eff[j];
        sum_grad += (ne_c - ne);
        sum_sv   += sv[NH + (r - 1) * NCOLS + c];
    }
    if (r < NROWS - 1) {
        const int j = j0 + NCOLS;
        const float ne = status[j] != 0 ? over[j] : eff[j];
        sum_grad += (ne - ne_c);
        sum_sv   += sv[NH + r * NCOLS + c];
    }
    const int cnt = (c > 0) + (c < NCOLS - 1) + (r > 0) + (r < NROWS - 1);
    const float rcnt = (cnt == 4) ? 0.25f : ((cnt == 3) ? (1.0f / 3.0f) : 0.5f);
    return finish_node(sum_grad, sum_sv, rcnt, ne_c, discharge[j0], geom[j0]);
}

__global__ __launch_bounds__(512)
void conduit_kernel(const float* __restrict__ eff,
                    const float* __restrict__ discharge,
                    const float* __restrict__ geom,
                    const float* __restrict__ over,
                    const float* __restrict__ sv,
                    const int*   __restrict__ status,
                    float* __restrict__ out)
{
    // bijective XCD chunk swizzle: nwg=2250, 8 XCDs -> q=281, rem=2
    const int orig = blockIdx.x;
    const int xcd  = orig & 7;
    const int base = orig >> 3;
    const int lin  = (xcd < 2) ? xcd * 282 + base
                               : 2 * 282 + (xcd - 2) * 281 + base;
    const int bx = lin % GX;           // col tile
    const int by = lin / GX;           // row tile (contiguous band per XCD)

    const int c0 = bx * 256 + threadIdx.x * 2;
    const int r  = by * 4 + threadIdx.y;
    if (c0 >= NCOLS) return;
    const int idx = r * NCOLS + c0;

    const bool interior = (r >= 2) && (r <= NROWS - 3) && (c0 >= 2) && (c0 <= NCOLS - 4);

    if (interior) {
        const float2 eC = *(const float2*)(eff + idx);
        const float2 eN = *(const float2*)(eff + idx - NCOLS);
        const float2 eS = *(const float2*)(eff + idx + NCOLS);
        const float  eW = eff[idx - 1];
        const float  eE = eff[idx + 2];
        const float2 q2 = *(const float2*)(discharge + idx);
        const float2 g2 = *(const float2*)(geom + idx);
        const float2 vN = *(const float2*)(sv + NH + (r - 1) * NCOLS + c0);
        const float2 vS = *(const float2*)(sv + NH + r * NCOLS + c0);
        const int hb = r * (NCOLS - 1) + c0 - 1;   // horizontal links c0-1, c0, c0+1
        const float h0 = sv[hb], h1 = sv[hb + 1], h2 = sv[hb + 2];

        float2 res;
        res.x = finish_node((eC.y - eW) + (eS.x - eN.x), h0 + h1 + vN.x + vS.x,
                            0.25f, eC.x, q2.x, g2.x);
        res.y = finish_node((eE - eC.x) + (eS.y - eN.y), h1 + h2 + vN.y + vS.y,
                            0.25f, eC.y, q2.y, g2.y);
        *(float2*)(out + idx) = res;
    } else {
        // rim-adjacent slow path: full per-node logic
        #pragma unroll
        for (int k = 0; k < 2; ++k) {
            const int c = c0 + k;
            if (c >= NCOLS) break;
            out[r * NCOLS + c] = slow_node(eff, discharge, geom, over, sv, status, r, c);
        }
    }
}

extern "C" void kernel_launch(void* const* d_in, const int* in_sizes, int n_in,
                              void* d_out, int out_size, void* d_ws, size_t ws_size,
                              hipStream_t stream) {
    const float* eff       = (const float*)d_in[0];
    const float* discharge = (const float*)d_in[1];
    const float* geom      = (const float*)d_in[2];
    const float* over      = (const float*)d_in[3];
    const float* sv        = (const float*)d_in[4];
    // d_in[5]=link_length constant; d_in[6]=head, d_in[7]=tail implied
    const int*   status    = (const int*)d_in[8];
    float* out = (float*)d_out;

    dim3 block(128, 4, 1);
    dim3 grid(NWG, 1, 1);
    conduit_kernel<<<grid, block, 0, stream>>>(eff, discharge, geom, over, sv, status, out);
}